// Round 7
// baseline (398.568 us; speedup 1.0000x reference)
//
#include <hip/hip_runtime.h>
#include <hip/hip_bf16.h>
#include <math.h>

#define B_BATCH 8
#define SEQ 2048
#define DIM 768
#define E3 2304   // 3*DIM

typedef __bf16 bf16x8 __attribute__((ext_vector_type(8)));
typedef float floatx4 __attribute__((ext_vector_type(4)));

__device__ __forceinline__ void load_lds_16B(const __hip_bfloat16* g, __hip_bfloat16* l) {
    __builtin_amdgcn_global_load_lds((const __attribute__((address_space(1))) void*)g,
                                     (__attribute__((address_space(3))) void*)l, 16, 0, 0);
}

template<typename T> __device__ __forceinline__ T to_out(float v);
template<> __device__ __forceinline__ float to_out<float>(float v) { return v; }
template<> __device__ __forceinline__ __hip_bfloat16 to_out<__hip_bfloat16>(float v) { return __float2bfloat16(v); }

// fp32 -> bf16 conversion, 8 elements per thread
__global__ __launch_bounds__(256, 4)
void cvt_f32_bf16(const float* __restrict__ in, __hip_bfloat16* __restrict__ out, long n8)
{
    const long i = (long)blockIdx.x * blockDim.x + threadIdx.x;
    if (i >= n8) return;
    const float4* p = (const float4*)in + i * 2;
    const float4 a = p[0], b = p[1];
    union { uint4 u; __hip_bfloat16 h[8]; } t;
    t.h[0] = __float2bfloat16(a.x); t.h[1] = __float2bfloat16(a.y);
    t.h[2] = __float2bfloat16(a.z); t.h[3] = __float2bfloat16(a.w);
    t.h[4] = __float2bfloat16(b.x); t.h[5] = __float2bfloat16(b.y);
    t.h[6] = __float2bfloat16(b.z); t.h[7] = __float2bfloat16(b.w);
    ((uint4*)out)[i] = t.u;
}

// 64x64 LDS-tiled transpose: out[c][r] = in[r][c].  grid (rows/64, cols/64, Z)
__global__ __launch_bounds__(256, 4)
void transpose64(const __hip_bfloat16* __restrict__ in, long ldi, long si,
                 __hip_bfloat16* __restrict__ out, long ldo, long so)
{
    __shared__ __hip_bfloat16 t[64][65];   // +1 pad
    in  += (long)blockIdx.z * si;
    out += (long)blockIdx.z * so;
    const int r0 = blockIdx.x * 64;   // row base in `in`
    const int c0 = blockIdx.y * 64;   // col base in `in`
    const int tid = threadIdx.x;
    const int r  = tid >> 3;          // 0..31
    const int c8 = (tid & 7) * 8;
#pragma unroll
    for (int h = 0; h < 2; ++h) {
        const int row = r + h * 32;
        union { uint4 u; __hip_bfloat16 v[8]; } tmp;
        tmp.u = *(const uint4*)(in + (long)(r0 + row) * ldi + c0 + c8);
#pragma unroll
        for (int j = 0; j < 8; ++j) t[row][c8 + j] = tmp.v[j];
    }
    __syncthreads();
#pragma unroll
    for (int h = 0; h < 2; ++h) {
        const int cr = r + h * 32;    // output row = input col
        union { uint4 u; __hip_bfloat16 v[8]; } tmp;
#pragma unroll
        for (int j = 0; j < 8; ++j) tmp.v[j] = t[c8 + j][cr];
        *(uint4*)(out + (long)(c0 + cr) * ldo + r0 + c8) = tmp.u;
    }
}

// C[M x N] = f( A [M x K] * B^T ), B is [N x K] row-major.  K % 64 == 0.
// r6 structure with ONE change: proper double-buffered 2-phase (catalog T3
// minimum recipe).  The stage of tile t+1 is issued BEFORE computing tile t,
// into the other LDS buffer; one __syncthreads() per tile.  Its implicit
// vmcnt(0) now waits on loads issued a full compute phase (~300cy of
// ds_read+MFMA) earlier -> load latency hidden under compute, instead of
// fully exposed as in r6 (stage -> drain -> compute same tile).
// Hazard audit: iter-t ds_reads drain before its MFMAs (compiler lgkmcnt),
// which precede the barrier; iter-t+1's overwriting stage issues after the
// barrier.  LDS 64 KB -> 2 blocks/CU (8 waves).
//
// Swizzle per 32-k half (verified r5/r6: 0 bank conflicts):
//   staging col = ((lane&3) - ((sr>>1)&3)) & 3    (counter-rotated global src)
//   read chunk  = (g + (fr>>1)) & 3               (rotated read col)
//
// EPI = 0: C = scale*AB^T + bias
// EPI = 1: C = exp(scale*AB^T); fp32 row sums atomically added into rs[]
// EPI = 2: C = (AB^T) * (1/rs[row])
// 1D grid = MB*NB*ZB.  XCD swizzle decode (audited r0): pairs = MB*ZB %8==0.
template<typename OutT, int EPI>
__global__ __launch_bounds__(256, 2)
void gemm128(const __hip_bfloat16* __restrict__ A, long lda, long sA,
             const __hip_bfloat16* __restrict__ Bm, long ldb, long sB,
             OutT* __restrict__ C, long ldc, long sC,
             const float* __restrict__ bias,
             float* __restrict__ rs, long srs,
             float scale, int K, int MB, int NB)
{
    __shared__ __hip_bfloat16 As[2][2][128 * 32];   // [buf][half], 8 KB each
    __shared__ __hip_bfloat16 Bs[2][2][128 * 32];   // total 64 KB

    const int id    = blockIdx.x;
    const int xcd   = id & 7;
    const int jj    = id >> 3;
    const int pairs = gridDim.x / NB;      // MB*ZB
    const int ppx   = pairs >> 3;
    const int pair  = xcd * ppx + jj / NB;
    const int nblk  = jj % NB;
    const int zblk  = pair / MB;
    const int mblk  = pair % MB;

    A  += (long)zblk * sA;
    Bm += (long)zblk * sB;
    C  += (long)zblk * sC;
    if constexpr (EPI != 0) rs += (long)zblk * srs;

    const int n0   = nblk * 128;
    const int m0   = mblk * 128;
    const int tid  = threadIdx.x;
    const int wave = tid >> 6;
    const int lane = tid & 63;
    const int wm   = (wave & 1) * 64;
    const int wn   = (wave >> 1) * 64;

    // staging: global_load_lds writes LDS at (uniform base) + lane*16B.
    const int sr  = lane >> 2;
    const int scs = ((((lane & 3) - ((sr >> 1) & 3)) & 3)) * 8;   // counter-rotated

    // MFMA A/B fragment: m(or n)=lane&15, k=(lane>>4)*8 + j  [verified m89/m91]
    const int fr  = lane & 15;
    const int g   = lane >> 4;
    const int fks = ((g + (fr >> 1)) & 3) * 8;                    // rotated read col

    floatx4 acc[4][4] = {};

    auto stage = [&](int k0, int buf) {
#pragma unroll
        for (int h = 0; h < 2; ++h)
#pragma unroll
        for (int c = 0; c < 2; ++c) {
            const int chunk = wave * 2 + c;            // wave-uniform
            const int row   = chunk * 16 + sr;
            load_lds_16B(A  + (long)(m0 + row) * lda + (k0 + h * 32 + scs),
                         As[buf][h] + chunk * 512);
            load_lds_16B(Bm + (long)(n0 + row) * ldb + (k0 + h * 32 + scs),
                         Bs[buf][h] + chunk * 512);
        }
    };

    // prologue: tile 0 staged and drained (implicit vmcnt(0) in syncthreads)
    stage(0, 0);
    __syncthreads();

    int cur = 0;
    for (int k0 = 0; k0 < K; k0 += 64) {
        if (k0 + 64 < K) stage(k0 + 64, cur ^ 1);     // prefetch next tile

#pragma unroll
        for (int h = 0; h < 2; ++h) {
            bf16x8 af[4], bfr[4];
#pragma unroll
            for (int i = 0; i < 4; ++i) {
                af[i]  = *(const bf16x8*)(As[cur][h] + (wm + i * 16 + fr) * 32 + fks);
                bfr[i] = *(const bf16x8*)(Bs[cur][h] + (wn + i * 16 + fr) * 32 + fks);
            }
#pragma unroll
            for (int mi = 0; mi < 4; ++mi)
#pragma unroll
                for (int ni = 0; ni < 4; ++ni)
                    acc[mi][ni] = __builtin_amdgcn_mfma_f32_16x16x32_bf16(
                        af[mi], bfr[ni], acc[mi][ni], 0, 0, 0);
        }
        __syncthreads();   // drains prefetch loads (issued one compute-phase ago)
        cur ^= 1;
    }

    // C/D layout: col = lane&15, row = (lane>>4)*4 + reg  [verified m89/m91]
    const int cr = g * 4;

    float bv[4];
    if constexpr (EPI == 0) {
#pragma unroll
        for (int ni = 0; ni < 4; ++ni)
            bv[ni] = bias ? bias[n0 + wn + ni * 16 + fr] : 0.0f;
    }

#pragma unroll
    for (int mi = 0; mi < 4; ++mi) {
#pragma unroll
        for (int r = 0; r < 4; ++r) {
            const int row = m0 + wm + mi * 16 + cr + r;
            float invv;
            if constexpr (EPI == 2) invv = 1.0f / rs[row];
            float s = 0.0f;
#pragma unroll
            for (int ni = 0; ni < 4; ++ni) {   // 4 consecutive 32B segments per row
                const int col = n0 + wn + ni * 16 + fr;
                float v = acc[mi][ni][r];
                if constexpr (EPI == 0)      v = v * scale + bv[ni];
                else if constexpr (EPI == 1) { v = __expf(v * scale); s += v; }
                else                         v = v * invv;
                C[(long)row * ldc + col] = to_out<OutT>(v);
            }
            if constexpr (EPI == 1) {
                // reduce over the 16 fr-lanes (cols); lanes share g -> same row
                s += __shfl_xor(s, 1, 64);
                s += __shfl_xor(s, 2, 64);
                s += __shfl_xor(s, 4, 64);
                s += __shfl_xor(s, 8, 64);
                if (fr == 0) atomicAdd(&rs[row], s);
            }
        }
    }
}

extern "C" void kernel_launch(void* const* d_in, const int* in_sizes, int n_in,
                              void* d_out, int out_size, void* d_ws, size_t ws_size,
                              hipStream_t stream)
{
    const float* x     = (const float*)d_in[0];
    const float* w_qkv = (const float*)d_in[1];
    const float* b_qkv = (const float*)d_in[2];
    const float* w_prj = (const float*)d_in[3];
    const float* b_prj = (const float*)d_in[4];
    float* out = (float*)d_out;

    const float alpha = 1.0f / (sqrtf((float)DIM) * 3.0f);  // qk scale / temperature

    const size_t XE   = (size_t)B_BATCH * SEQ * DIM;   // 12.58M (also Vt size)
    const size_t WQE  = (size_t)E3 * DIM;
    const size_t WPE  = (size_t)DIM * DIM;
    const size_t QKVE = (size_t)B_BATCH * SEQ * E3;
    const size_t SE   = (size_t)B_BATCH * SEQ * SEQ;
    const size_t OE   = XE;
    const size_t RSE  = (size_t)B_BATCH * SEQ;         // fp32 row sums
    dim3 blk(256);

    const size_t full_bytes = (XE + WQE + WPE + QKVE + SE + OE) * sizeof(__hip_bfloat16)
                            + RSE * sizeof(float);

    if (ws_size >= full_bytes) {
        __hip_bfloat16* xb  = (__hip_bfloat16*)d_ws;   // x-bf16, then reused as Vt
        __hip_bfloat16* wqb = xb + XE;
        __hip_bfloat16* wpb = wqb + WQE;
        __hip_bfloat16* qkv = wpb + WPE;
        __hip_bfloat16* S   = qkv + QKVE;              // holds E = exp(alpha*QK^T)
        __hip_bfloat16* O   = S + SE;
        float*          RS  = (float*)(O + OE);
        __hip_bfloat16* Vt  = xb;                      // xb dead after QKV GEMM

        cvt_f32_bf16<<<dim3((XE / 8 + 255) / 256), blk, 0, stream>>>(x, xb, XE / 8);
        cvt_f32_bf16<<<dim3((WQE / 8 + 255) / 256), blk, 0, stream>>>(w_qkv, wqb, WQE / 8);
        cvt_f32_bf16<<<dim3((WPE / 8 + 255) / 256), blk, 0, stream>>>(w_prj, wpb, WPE / 8);
        hipMemsetAsync(RS, 0, RSE * sizeof(float), stream);

        // qkv = x @ w_qkv^T + b   [16384 x 2304]   pairs=128
        gemm128<__hip_bfloat16, 0><<<dim3(128 * 18), blk, 0, stream>>>(
            xb, DIM, 0, wqb, DIM, 0, qkv, E3, 0, b_qkv, nullptr, 0, 1.0f, DIM, 128, 18);
        // Vt[b] = V[b]^T  [768 x 2048] per batch
        transpose64<<<dim3(SEQ / 64, DIM / 64, B_BATCH), blk, 0, stream>>>(
            qkv + 2 * DIM, E3, (long)SEQ * E3, Vt, SEQ, (long)DIM * SEQ);
        // E = exp(alpha * Q @ K^T), rowsums -> RS   [8][2048 x 2048]   pairs=128
        gemm128<__hip_bfloat16, 1><<<dim3(16 * 16 * B_BATCH), blk, 0, stream>>>(
            qkv, E3, (long)SEQ * E3, qkv + DIM, E3, (long)SEQ * E3,
            S, SEQ, (long)SEQ * SEQ, nullptr, RS, SEQ, alpha, DIM, 16, 16);
        // O = (E @ Vt^T) / RS[row]   [8][2048 x 768]   pairs=128
        gemm128<__hip_bfloat16, 2><<<dim3(16 * 6 * B_BATCH), blk, 0, stream>>>(
            S, SEQ, (long)SEQ * SEQ, Vt, SEQ, (long)DIM * SEQ,
            O, DIM, (long)SEQ * DIM, nullptr, RS, SEQ, 1.0f, SEQ, 16, 6);
        // out = O @ w_proj^T + b  [16384 x 768] fp32   pairs=128
        gemm128<float, 0><<<dim3(128 * 6), blk, 0, stream>>>(
            O, DIM, 0, wpb, DIM, 0, out, DIM, 0, b_prj, nullptr, 0, 1.0f, DIM, 128, 6);
    } else {
        // minimal-workspace fallback: per-batch pipeline (~30 MB scratch)
        const size_t xE  = (size_t)SEQ * DIM;
        const size_t qE  = (size_t)SEQ * E3;
        const size_t sE1 = (size_t)SEQ * SEQ;
        __hip_bfloat16* wqb = (__hip_bfloat16*)d_ws;
        __hip_bfloat16* wpb = wqb + WQE;
        __hip_bfloat16* xb  = wpb + WPE;            // reused as Vt per batch
        __hip_bfloat16* qkv = xb + xE;
        __hip_bfloat16* S   = qkv + qE;
        __hip_bfloat16* O   = S + sE1;
        float*          RS  = (float*)(O + xE);
        __hip_bfloat16* Vt  = xb;

        cvt_f32_bf16<<<dim3((WQE / 8 + 255) / 256), blk, 0, stream>>>(w_qkv, wqb, WQE / 8);
        cvt_f32_bf16<<<dim3((WPE / 8 + 255) / 256), blk, 0, stream>>>(w_prj, wpb, WPE / 8);

        for (int b = 0; b < B_BATCH; ++b) {
            const float* xf = x + (size_t)b * xE;
            cvt_f32_bf16<<<dim3((xE / 8 + 255) / 256), blk, 0, stream>>>(xf, xb, xE / 8);
            hipMemsetAsync(RS, 0, SEQ * sizeof(float), stream);
            gemm128<__hip_bfloat16, 0><<<dim3(16 * 18), blk, 0, stream>>>(
                xb, DIM, 0, wqb, DIM, 0, qkv, E3, 0, b_qkv, nullptr, 0, 1.0f, DIM, 16, 18);
            transpose64<<<dim3(SEQ / 64, DIM / 64, 1), blk, 0, stream>>>(
                qkv + 2 * DIM, E3, 0, Vt, SEQ, 0);
            gemm128<__hip_bfloat16, 1><<<dim3(16 * 16), blk, 0, stream>>>(
                qkv, E3, 0, qkv + DIM, E3, 0, S, SEQ, 0, nullptr, RS, 0, alpha, DIM, 16, 16);
            gemm128<__hip_bfloat16, 2><<<dim3(16 * 6), blk, 0, stream>>>(
                S, SEQ, 0, Vt, SEQ, 0, O, DIM, 0, nullptr, RS, 0, 1.0f, SEQ, 16, 6);
            gemm128<float, 0><<<dim3(16 * 6), blk, 0, stream>>>(
                O, DIM, 0, wpb, DIM, 0, out + (size_t)b * xE, DIM, 0, b_prj, nullptr, 0, 1.0f, DIM, 16, 6);
        }
    }
}

// Round 8
// 374.166 us; speedup vs baseline: 1.0652x; 1.0652x over previous
//
#include <hip/hip_runtime.h>
#include <hip/hip_bf16.h>
#include <math.h>

#define B_BATCH 8
#define SEQ 2048
#define DIM 768
#define E3 2304   // 3*DIM

typedef __bf16 bf16x8 __attribute__((ext_vector_type(8)));
typedef float floatx4 __attribute__((ext_vector_type(4)));

__device__ __forceinline__ void load_lds_16B(const __hip_bfloat16* g, __hip_bfloat16* l) {
    __builtin_amdgcn_global_load_lds((const __attribute__((address_space(1))) void*)g,
                                     (__attribute__((address_space(3))) void*)l, 16, 0, 0);
}

#define MEMFENCE asm volatile("" ::: "memory")
#define BAR() do { MEMFENCE; __builtin_amdgcn_s_barrier(); MEMFENCE; } while (0)
#define WAITVM(N) asm volatile("s_waitcnt vmcnt(" #N ")" ::: "memory")

template<typename T> __device__ __forceinline__ T to_out(float v);
template<> __device__ __forceinline__ float to_out<float>(float v) { return v; }
template<> __device__ __forceinline__ __hip_bfloat16 to_out<__hip_bfloat16>(float v) { return __float2bfloat16(v); }

// fp32 -> bf16 conversion, 8 elements per thread
__global__ __launch_bounds__(256, 4)
void cvt_f32_bf16(const float* __restrict__ in, __hip_bfloat16* __restrict__ out, long n8)
{
    const long i = (long)blockIdx.x * blockDim.x + threadIdx.x;
    if (i >= n8) return;
    const float4* p = (const float4*)in + i * 2;
    const float4 a = p[0], b = p[1];
    union { uint4 u; __hip_bfloat16 h[8]; } t;
    t.h[0] = __float2bfloat16(a.x); t.h[1] = __float2bfloat16(a.y);
    t.h[2] = __float2bfloat16(a.z); t.h[3] = __float2bfloat16(a.w);
    t.h[4] = __float2bfloat16(b.x); t.h[5] = __float2bfloat16(b.y);
    t.h[6] = __float2bfloat16(b.z); t.h[7] = __float2bfloat16(b.w);
    ((uint4*)out)[i] = t.u;
}

// 64x64 LDS-tiled transpose: out[c][r] = in[r][c].  grid (rows/64, cols/64, Z)
__global__ __launch_bounds__(256, 4)
void transpose64(const __hip_bfloat16* __restrict__ in, long ldi, long si,
                 __hip_bfloat16* __restrict__ out, long ldo, long so)
{
    __shared__ __hip_bfloat16 t[64][65];   // +1 pad
    in  += (long)blockIdx.z * si;
    out += (long)blockIdx.z * so;
    const int r0 = blockIdx.x * 64;   // row base in `in`
    const int c0 = blockIdx.y * 64;   // col base in `in`
    const int tid = threadIdx.x;
    const int r  = tid >> 3;          // 0..31
    const int c8 = (tid & 7) * 8;
#pragma unroll
    for (int h = 0; h < 2; ++h) {
        const int row = r + h * 32;
        union { uint4 u; __hip_bfloat16 v[8]; } tmp;
        tmp.u = *(const uint4*)(in + (long)(r0 + row) * ldi + c0 + c8);
#pragma unroll
        for (int j = 0; j < 8; ++j) t[row][c8 + j] = tmp.v[j];
    }
    __syncthreads();
#pragma unroll
    for (int h = 0; h < 2; ++h) {
        const int cr = r + h * 32;    // output row = input col
        union { uint4 u; __hip_bfloat16 v[8]; } tmp;
#pragma unroll
        for (int j = 0; j < 8; ++j) tmp.v[j] = t[c8 + j][cr];
        *(uint4*)(out + (long)(c0 + cr) * ldo + r0 + c8) = tmp.u;
    }
}

// C[M x N] = f( A [M x K] * B^T ), B is [N x K] row-major.  K % 32 == 0, K>=96.
//
// r6 (358us best: BK=64, stage->drain->compute, ~2.8 blocks/CU) +
// T4 counted-vmcnt ring (r7 post-mortem: dbuf with vmcnt(0) drain halved
// occupancy and LOST; the fix must remove the drain, not just add a buffer):
//   3 buffers x BK=32 (48 KB -> 3 blocks/CU), prefetch distance 2.
//   Per iter: stage(t+2 -> buf[(t+2)%3]); ds_read frags from buf[t%3];
//   16 MFMA; WAITVM(4); raw s_barrier.
//   vmcnt ledger (4 loads/tile/wave): after stage, outstanding = {t+1,t+2}x4
//   = 8 -> vmcnt(4) drains exactly tile t+1.  Each wave waits on its OWN
//   loads; barrier then makes all waves' t+1 chunks visible.  NEVER vmcnt(0)
//   in steady state (the m201/m218 mechanism, +38% counted-vs-drain0).
//   Tail: t==NT-2 -> WAITVM(0); t==NT-1 -> no wait, no barrier.
//   Overwrite safety: buf[(t+2)%3] last ds_read at iter t-1, complete
//   (lgkm before MFMA) before that iter's closing barrier.
//   Raw s_barrier (NOT __syncthreads) keeps the counted wait alive.
//
// Swizzle per 32-k buffer (verified r5/r6: 0 bank conflicts):
//   staging col = ((lane&3) - ((sr>>1)&3)) & 3    (counter-rotated global src)
//   read chunk  = (g + (fr>>1)) & 3               (rotated read col)
//
// EPI = 0: C = scale*AB^T + bias
// EPI = 1: C = exp(scale*AB^T); fp32 row sums atomically added into rs[]
// EPI = 2: C = (AB^T) * (1/rs[row])
// 1D grid = MB*NB*ZB.  XCD swizzle decode (audited r0): pairs = MB*ZB %8==0.
template<typename OutT, int EPI>
__global__ __launch_bounds__(256, 3)
void gemm128(const __hip_bfloat16* __restrict__ A, long lda, long sA,
             const __hip_bfloat16* __restrict__ Bm, long ldb, long sB,
             OutT* __restrict__ C, long ldc, long sC,
             const float* __restrict__ bias,
             float* __restrict__ rs, long srs,
             float scale, int K, int MB, int NB)
{
    __shared__ __hip_bfloat16 As[3][128 * 32];   // 8 KB each
    __shared__ __hip_bfloat16 Bs[3][128 * 32];   // total 48 KB -> 3 blocks/CU

    const int id    = blockIdx.x;
    const int xcd   = id & 7;
    const int jj    = id >> 3;
    const int pairs = gridDim.x / NB;      // MB*ZB
    const int ppx   = pairs >> 3;
    const int pair  = xcd * ppx + jj / NB;
    const int nblk  = jj % NB;
    const int zblk  = pair / MB;
    const int mblk  = pair % MB;

    A  += (long)zblk * sA;
    Bm += (long)zblk * sB;
    C  += (long)zblk * sC;
    if constexpr (EPI != 0) rs += (long)zblk * srs;

    const int n0   = nblk * 128;
    const int m0   = mblk * 128;
    const int tid  = threadIdx.x;
    const int wave = tid >> 6;
    const int lane = tid & 63;
    const int wm   = (wave & 1) * 64;
    const int wn   = (wave >> 1) * 64;

    // staging: global_load_lds writes LDS at (uniform base) + lane*16B.
    const int sr  = lane >> 2;
    const int scs = ((((lane & 3) - ((sr >> 1) & 3)) & 3)) * 8;   // counter-rotated

    // MFMA A/B fragment: m(or n)=lane&15, k=(lane>>4)*8 + j  [verified m89/m91]
    const int fr  = lane & 15;
    const int g   = lane >> 4;
    const int fks = ((g + (fr >> 1)) & 3) * 8;                    // rotated read col

    floatx4 acc[4][4] = {};

    const int NT = K >> 5;                         // 32-K tiles (>= 3 here)

    auto stage = [&](int t, int buf) {
#pragma unroll
        for (int c = 0; c < 2; ++c) {
            const int chunk = wave * 2 + c;        // wave-uniform
            const int row   = chunk * 16 + sr;
            load_lds_16B(A  + (long)(m0 + row) * lda + (t * 32 + scs), As[buf] + chunk * 512);
            load_lds_16B(Bm + (long)(n0 + row) * ldb + (t * 32 + scs), Bs[buf] + chunk * 512);
        }
    };

    auto body = [&](int t, int B) __attribute__((always_inline)) {
        if (t + 2 < NT) stage(t + 2, (B + 2) % 3);       // B literal -> folds
        bf16x8 af[4], bfr[4];
#pragma unroll
        for (int i = 0; i < 4; ++i) {
            af[i]  = *(const bf16x8*)(As[B] + (wm + i * 16 + fr) * 32 + fks);
            bfr[i] = *(const bf16x8*)(Bs[B] + (wn + i * 16 + fr) * 32 + fks);
        }
#pragma unroll
        for (int mi = 0; mi < 4; ++mi)
#pragma unroll
            for (int ni = 0; ni < 4; ++ni)
                acc[mi][ni] = __builtin_amdgcn_mfma_f32_16x16x32_bf16(
                    af[mi], bfr[ni], acc[mi][ni], 0, 0, 0);
        if (t + 2 < NT)      { WAITVM(4); }
        else if (t + 1 < NT) { WAITVM(0); }
        if (t + 1 < NT) BAR();
    };

    // prologue: tiles 0,1 in flight; drain tile 0 only (4 of 8 outstanding)
    stage(0, 0); stage(1, 1);
    WAITVM(4);
    BAR();

    int tb = 0;
    for (; tb + 3 <= NT; tb += 3) {                // tb stays == 0 mod 3
        body(tb + 0, 0);
        body(tb + 1, 1);
        body(tb + 2, 2);
    }
    if (tb + 0 < NT) body(tb + 0, 0);              // NT%3 == 1 case (PV: NT=64)
    if (tb + 1 < NT) body(tb + 1, 1);

    // C/D layout: col = lane&15, row = (lane>>4)*4 + reg  [verified m89/m91]
    const int cr = g * 4;

    float bv[4];
    if constexpr (EPI == 0) {
#pragma unroll
        for (int ni = 0; ni < 4; ++ni)
            bv[ni] = bias ? bias[n0 + wn + ni * 16 + fr] : 0.0f;
    }

#pragma unroll
    for (int mi = 0; mi < 4; ++mi) {
#pragma unroll
        for (int r = 0; r < 4; ++r) {
            const int row = m0 + wm + mi * 16 + cr + r;
            float invv;
            if constexpr (EPI == 2) invv = 1.0f / rs[row];
            float s = 0.0f;
#pragma unroll
            for (int ni = 0; ni < 4; ++ni) {   // 4 consecutive 32B segments per row
                const int col = n0 + wn + ni * 16 + fr;
                float v = acc[mi][ni][r];
                if constexpr (EPI == 0)      v = v * scale + bv[ni];
                else if constexpr (EPI == 1) { v = __expf(v * scale); s += v; }
                else                         v = v * invv;
                C[(long)row * ldc + col] = to_out<OutT>(v);
            }
            if constexpr (EPI == 1) {
                // reduce over the 16 fr-lanes (cols); lanes share g -> same row
                s += __shfl_xor(s, 1, 64);
                s += __shfl_xor(s, 2, 64);
                s += __shfl_xor(s, 4, 64);
                s += __shfl_xor(s, 8, 64);
                if (fr == 0) atomicAdd(&rs[row], s);
            }
        }
    }
}

extern "C" void kernel_launch(void* const* d_in, const int* in_sizes, int n_in,
                              void* d_out, int out_size, void* d_ws, size_t ws_size,
                              hipStream_t stream)
{
    const float* x     = (const float*)d_in[0];
    const float* w_qkv = (const float*)d_in[1];
    const float* b_qkv = (const float*)d_in[2];
    const float* w_prj = (const float*)d_in[3];
    const float* b_prj = (const float*)d_in[4];
    float* out = (float*)d_out;

    const float alpha = 1.0f / (sqrtf((float)DIM) * 3.0f);  // qk scale / temperature

    const size_t XE   = (size_t)B_BATCH * SEQ * DIM;   // 12.58M (also Vt size)
    const size_t WQE  = (size_t)E3 * DIM;
    const size_t WPE  = (size_t)DIM * DIM;
    const size_t QKVE = (size_t)B_BATCH * SEQ * E3;
    const size_t SE   = (size_t)B_BATCH * SEQ * SEQ;
    const size_t OE   = XE;
    const size_t RSE  = (size_t)B_BATCH * SEQ;         // fp32 row sums
    dim3 blk(256);

    const size_t full_bytes = (XE + WQE + WPE + QKVE + SE + OE) * sizeof(__hip_bfloat16)
                            + RSE * sizeof(float);

    if (ws_size >= full_bytes) {
        __hip_bfloat16* xb  = (__hip_bfloat16*)d_ws;   // x-bf16, then reused as Vt
        __hip_bfloat16* wqb = xb + XE;
        __hip_bfloat16* wpb = wqb + WQE;
        __hip_bfloat16* qkv = wpb + WPE;
        __hip_bfloat16* S   = qkv + QKVE;              // holds E = exp(alpha*QK^T)
        __hip_bfloat16* O   = S + SE;
        float*          RS  = (float*)(O + OE);
        __hip_bfloat16* Vt  = xb;                      // xb dead after QKV GEMM

        cvt_f32_bf16<<<dim3((XE / 8 + 255) / 256), blk, 0, stream>>>(x, xb, XE / 8);
        cvt_f32_bf16<<<dim3((WQE / 8 + 255) / 256), blk, 0, stream>>>(w_qkv, wqb, WQE / 8);
        cvt_f32_bf16<<<dim3((WPE / 8 + 255) / 256), blk, 0, stream>>>(w_prj, wpb, WPE / 8);
        hipMemsetAsync(RS, 0, RSE * sizeof(float), stream);

        // qkv = x @ w_qkv^T + b   [16384 x 2304]   pairs=128
        gemm128<__hip_bfloat16, 0><<<dim3(128 * 18), blk, 0, stream>>>(
            xb, DIM, 0, wqb, DIM, 0, qkv, E3, 0, b_qkv, nullptr, 0, 1.0f, DIM, 128, 18);
        // Vt[b] = V[b]^T  [768 x 2048] per batch
        transpose64<<<dim3(SEQ / 64, DIM / 64, B_BATCH), blk, 0, stream>>>(
            qkv + 2 * DIM, E3, (long)SEQ * E3, Vt, SEQ, (long)DIM * SEQ);
        // E = exp(alpha * Q @ K^T), rowsums -> RS   [8][2048 x 2048]   pairs=128
        gemm128<__hip_bfloat16, 1><<<dim3(16 * 16 * B_BATCH), blk, 0, stream>>>(
            qkv, E3, (long)SEQ * E3, qkv + DIM, E3, (long)SEQ * E3,
            S, SEQ, (long)SEQ * SEQ, nullptr, RS, SEQ, alpha, DIM, 16, 16);
        // O = (E @ Vt^T) / RS[row]   [8][2048 x 768]   pairs=128
        gemm128<__hip_bfloat16, 2><<<dim3(16 * 6 * B_BATCH), blk, 0, stream>>>(
            S, SEQ, (long)SEQ * SEQ, Vt, SEQ, (long)DIM * SEQ,
            O, DIM, (long)SEQ * DIM, nullptr, RS, SEQ, 1.0f, SEQ, 16, 6);
        // out = O @ w_proj^T + b  [16384 x 768] fp32   pairs=128
        gemm128<float, 0><<<dim3(128 * 6), blk, 0, stream>>>(
            O, DIM, 0, wpb, DIM, 0, out, DIM, 0, b_prj, nullptr, 0, 1.0f, DIM, 128, 6);
    } else {
        // minimal-workspace fallback: per-batch pipeline (~30 MB scratch)
        const size_t xE  = (size_t)SEQ * DIM;
        const size_t qE  = (size_t)SEQ * E3;
        const size_t sE1 = (size_t)SEQ * SEQ;
        __hip_bfloat16* wqb = (__hip_bfloat16*)d_ws;
        __hip_bfloat16* wpb = wqb + WQE;
        __hip_bfloat16* xb  = wpb + WPE;            // reused as Vt per batch
        __hip_bfloat16* qkv = xb + xE;
        __hip_bfloat16* S   = qkv + qE;
        __hip_bfloat16* O   = S + sE1;
        float*          RS  = (float*)(O + xE);
        __hip_bfloat16* Vt  = xb;

        cvt_f32_bf16<<<dim3((WQE / 8 + 255) / 256), blk, 0, stream>>>(w_qkv, wqb, WQE / 8);
        cvt_f32_bf16<<<dim3((WPE / 8 + 255) / 256), blk, 0, stream>>>(w_prj, wpb, WPE / 8);

        for (int b = 0; b < B_BATCH; ++b) {
            const float* xf = x + (size_t)b * xE;
            cvt_f32_bf16<<<dim3((xE / 8 + 255) / 256), blk, 0, stream>>>(xf, xb, xE / 8);
            hipMemsetAsync(RS, 0, SEQ * sizeof(float), stream);
            gemm128<__hip_bfloat16, 0><<<dim3(16 * 18), blk, 0, stream>>>(
                xb, DIM, 0, wqb, DIM, 0, qkv, E3, 0, b_qkv, nullptr, 0, 1.0f, DIM, 16, 18);
            transpose64<<<dim3(SEQ / 64, DIM / 64, 1), blk, 0, stream>>>(
                qkv + 2 * DIM, E3, 0, Vt, SEQ, 0);
            gemm128<__hip_bfloat16, 1><<<dim3(16 * 16), blk, 0, stream>>>(
                qkv, E3, 0, qkv + DIM, E3, 0, S, SEQ, 0, nullptr, RS, 0, alpha, DIM, 16, 16);
            gemm128<__hip_bfloat16, 2><<<dim3(16 * 6), blk, 0, stream>>>(
                S, SEQ, 0, Vt, SEQ, 0, O, DIM, 0, nullptr, RS, 0, 1.0f, SEQ, 16, 6);
            gemm128<float, 0><<<dim3(16 * 6), blk, 0, stream>>>(
                O, DIM, 0, wpb, DIM, 0, out + (size_t)b * xE, DIM, 0, b_prj, nullptr, 0, 1.0f, DIM, 16, 6);
        }
    }
}